// Round 2
// baseline (429.457 us; speedup 1.0000x reference)
//
#include <hip/hip_runtime.h>

// RoPE: out[...,2k]   = cos(a_k)*x[2k] - sin(a_k)*x[2k+1]
//       out[...,2k+1] = sin(a_k)*x[2k] + cos(a_k)*x[2k+1]
// a_k = pos * 10000^(-2k/128), k in [0,64), rows = 4*32*4096, D=128.
//
// v2b: hoist trig into a 2 MiB (cos,sin) LUT over (pos in [0,4096)) x
// (k in [0,64)) built by a prologue kernel; main kernel is pure
// streaming. v2 failed to compile: __builtin_nontemporal_* needs a
// native vector type, not HIP_vector_type<float,4> -> use
// ext_vector_type(4) alias for the streamed loads/stores.

#define BLOCK 256
#define MAX_POS 4096
#define DK2 64            // D_K / 2

typedef float vf4 __attribute__((ext_vector_type(4)));

// tab[p*64 + k] = (cos(p*invf_k), sin(p*invf_k)) as float2
__global__ __launch_bounds__(BLOCK) void rope_table(float2* __restrict__ tab)
{
    int tid = blockIdx.x * BLOCK + threadIdx.x;   // 0 .. 262143
    int p = tid >> 6;         // position
    int k = tid & 63;         // frequency index
    // inv_freq_k = 10000^(-k/64) = exp2(k * -log2(10000)/64)
    const float c = -0.2076205059304601f;  // -log2(10000)/64
    float a = (float)p * exp2f((float)k * c);
    float s, co;
    sincosf(a, &s, &co);      // accurate path; once per (p,k), not per element
    tab[tid] = make_float2(co, s);
}

__global__ __launch_bounds__(BLOCK) void rope_main(
    const vf4* __restrict__ x,
    const int* __restrict__ pos,
    const vf4* __restrict__ tab,   // 32 float4 per position: (c0,s0,c1,s1)...
    vf4* __restrict__ out,
    int n_f4)
{
    int stride = gridDim.x * BLOCK;
    for (int tid = blockIdx.x * BLOCK + threadIdx.x; tid < n_f4; tid += stride) {
        int row = tid >> 5;        // 32 float4 per 128-float row
        int j   = tid & 31;        // float4 index within row -> pairs 2j, 2j+1

        int p = pos[row];                               // wave-broadcast-ish load
        vf4 t = tab[p * 32 + j];                        // (c0,s0,c1,s1), L2-hit
        vf4 v = __builtin_nontemporal_load(&x[tid]);    // streaming read

        vf4 r;
        r.x = t.x * v.x - t.y * v.y;
        r.y = t.y * v.x + t.x * v.y;
        r.z = t.z * v.z - t.w * v.w;
        r.w = t.w * v.z + t.z * v.w;
        __builtin_nontemporal_store(r, &out[tid]);      // streaming write
    }
}

extern "C" void kernel_launch(void* const* d_in, const int* in_sizes, int n_in,
                              void* d_out, int out_size, void* d_ws, size_t ws_size,
                              hipStream_t stream) {
    const vf4* x   = (const vf4*)d_in[0];
    const int* pos = (const int*)d_in[1];
    vf4* out       = (vf4*)d_out;
    float2* tab    = (float2*)d_ws;      // 4096 * 64 * 8 B = 2 MiB

    // Prologue: build the (cos,sin) table. 262,144 threads, ~few us.
    rope_table<<<(MAX_POS * DK2) / BLOCK, BLOCK, 0, stream>>>(tab);

    int n_f4 = out_size / 4;               // 16,777,216
    int blocks = (n_f4 + BLOCK - 1) / BLOCK;
    if (blocks > 2048) blocks = 2048;      // grid-stride; ~8 blocks/CU
    rope_main<<<blocks, BLOCK, 0, stream>>>(x, pos, (const vf4*)tab, out, n_f4);
}

// Round 3
// 427.271 us; speedup vs baseline: 1.0051x; 1.0051x over previous
//
#include <hip/hip_runtime.h>

// RoPE: out[...,2k]   = cos(a_k)*x[2k] - sin(a_k)*x[2k+1]
//       out[...,2k+1] = sin(a_k)*x[2k] + cos(a_k)*x[2k+1]
// a_k = pos * 10000^(-2k/128), k in [0,64), rows = 4*32*4096, D=128.
//
// v3: single kernel again. Evidence from rounds 0-2: rope dispatches never
// appear in the top-5 (all fills at ~165us) -> kernel itself is < 164us,
// i.e. already ~memory-bound (~86us ideal); the 416us dur_us includes
// ~330us of harness 1-GiB poison fills in the timed window. The v2 LUT
// prologue was pure tax (+13us). sincosf (~25-30us machine-wide VALU,
// angles < 2^12 so medium reduction path) hides under memory latency.
// Keep: nontemporal streaming hints on x/out, 2048-block grid-stride.

#define BLOCK 256

typedef float vf4 __attribute__((ext_vector_type(4)));

__global__ __launch_bounds__(BLOCK) void rope_kernel(
    const vf4* __restrict__ x,
    const int* __restrict__ pos,
    vf4* __restrict__ out,
    int n_f4)
{
    int stride = gridDim.x * BLOCK;
    for (int tid = blockIdx.x * BLOCK + threadIdx.x; tid < n_f4; tid += stride) {
        int row = tid >> 5;        // 32 float4 per 128-float row
        int j   = tid & 31;        // float4 index within row -> pairs 2j, 2j+1

        float p = (float)pos[row];                      // broadcast within 32 lanes
        vf4 v = __builtin_nontemporal_load(&x[tid]);    // streaming read

        // inv_freq_k = 10000^(-k/64) = exp2(k * -log2(10000)/64)
        const float c = -0.2076205059304601f;  // -log2(10000)/64
        float k0 = (float)(2 * j);
        float a0 = p * exp2f(k0 * c);
        float a1 = p * exp2f((k0 + 1.0f) * c);

        float s0, c0, s1, c1;
        sincosf(a0, &s0, &c0);   // accurate path; hidden under memory traffic
        sincosf(a1, &s1, &c1);

        vf4 r;
        r.x = c0 * v.x - s0 * v.y;
        r.y = s0 * v.x + c0 * v.y;
        r.z = s1 * v.z - c1 * v.w;   // note: placeholder order fixed below
        r.w = 0.0f;
        // (correct forms)
        r.z = c1 * v.z - s1 * v.w;
        r.w = s1 * v.z + c1 * v.w;
        __builtin_nontemporal_store(r, &out[tid]);      // streaming write
    }
}

extern "C" void kernel_launch(void* const* d_in, const int* in_sizes, int n_in,
                              void* d_out, int out_size, void* d_ws, size_t ws_size,
                              hipStream_t stream) {
    const vf4* x   = (const vf4*)d_in[0];
    const int* pos = (const int*)d_in[1];
    vf4* out       = (vf4*)d_out;

    int n_f4 = out_size / 4;               // 16,777,216
    int blocks = (n_f4 + BLOCK - 1) / BLOCK;
    if (blocks > 2048) blocks = 2048;      // grid-stride; ~8 blocks/CU
    rope_kernel<<<blocks, BLOCK, 0, stream>>>(x, pos, out, n_f4);
}

// Round 4
// 413.037 us; speedup vs baseline: 1.0398x; 1.0345x over previous
//
#include <hip/hip_runtime.h>

// RoPE: out[...,2k]   = cos(a_k)*x[2k] - sin(a_k)*x[2k+1]
//       out[...,2k+1] = sin(a_k)*x[2k] + cos(a_k)*x[2k+1]
// a_k = pos * 10000^(-2k/128), k in [0,64), rows = 4*32*4096, D=128.
// One thread per float4 (2 pairs, 16B/lane coalesced).
//
// v4 = exact revert to round-0 best (416 us). Session evidence:
//  - rope dispatch never in rocprof top-5; ~330us of the timed window is
//    harness 1-GiB fills. Kernel portion ~86us vs ~83us streaming roofline
//    (539 MB at the fill-demonstrated 6.5 TB/s) -> ~96% of achievable BW.
//  - sincosf VALU (~20us machine-wide) hides fully under memory traffic;
//    the 2 MiB LUT prologue was +13us pure tax (v2b: 429).
//  - grid-stride@2048 + nontemporal hints regressed ~11us (v3: 427) vs
//    one-element-per-thread full-grid launch. Max memory parallelism wins.

#define BLOCK 256

__global__ __launch_bounds__(BLOCK) void rope_kernel(
    const float4* __restrict__ x,
    const int* __restrict__ pos,
    float4* __restrict__ out,
    int n_f4)
{
    int tid = blockIdx.x * BLOCK + threadIdx.x;
    if (tid >= n_f4) return;

    int row = tid >> 5;        // 32 float4 per row of 128
    int j   = tid & 31;        // float4 index within row -> pairs 2j, 2j+1

    float p = (float)pos[row]; // wave-broadcast load (same addr for 32 lanes)
    float4 v = x[tid];

    // inv_freq_k = 10000^(-k/64) = exp2(k * -log2(10000)/64)
    const float c = -0.2076205059304601f;  // -log2(10000)/64
    float k0 = (float)(2 * j);
    float a0 = p * exp2f(k0 * c);
    float a1 = p * exp2f((k0 + 1.0f) * c);

    float s0, c0, s1, c1;
    sincosf(a0, &s0, &c0);   // accurate version: angles up to ~4095 rad
    sincosf(a1, &s1, &c1);

    float4 r;
    r.x = c0 * v.x - s0 * v.y;
    r.y = s0 * v.x + c0 * v.y;
    r.z = c1 * v.z - s1 * v.w;
    r.w = s1 * v.z + c1 * v.w;
    out[tid] = r;
}

extern "C" void kernel_launch(void* const* d_in, const int* in_sizes, int n_in,
                              void* d_out, int out_size, void* d_ws, size_t ws_size,
                              hipStream_t stream) {
    const float4* x  = (const float4*)d_in[0];
    const int* pos   = (const int*)d_in[1];
    float4* out      = (float4*)d_out;

    int n_f4 = out_size / 4;               // 16,777,216
    int blocks = (n_f4 + BLOCK - 1) / BLOCK;
    rope_kernel<<<blocks, BLOCK, 0, stream>>>(x, pos, out, n_f4);
}